// Round 2
// baseline (349.135 us; speedup 1.0000x reference)
//
#include <hip/hip_runtime.h>

#define E_TOTAL 262144
#define TPB 256
#define NBLK 512
#define EPT 2
#define W0_LDS_STRIDE 516   // 512 + 4 pad -> distinct 4-bank spans per pair type
#define W1_LDS_STRIDE 260   // 256 + 4 pad

__device__ __forceinline__ float silu_f(float x) {
    return x / (1.0f + __expf(-x));
}

// PHASE 0: compute out1[32], accumulate per-channel sum/sumsq (BN1 stats)
// PHASE 1: recompute out1, apply BN1+SiLU, matvec W1 -> out2[8], accumulate BN2 stats
// PHASE 2: full recompute, apply BN2+SiLU, write output
template<int PHASE>
__global__ __launch_bounds__(TPB, 4)   // cap <=128 VGPR: avoid spill (round1: 256 VGPR, 269MB scratch writes)
void nep_main(const int* __restrict__ ij,
              const float* __restrict__ fn,
              const float* __restrict__ W0g,
              const float* __restrict__ W1g,
              const float* __restrict__ ab1,
              const float* __restrict__ ab2,
              float* __restrict__ partial,
              float* __restrict__ out)
{
    __shared__ __align__(16) float sW0[16 * W0_LDS_STRIDE];
    __shared__ __align__(16) float sW1[(PHASE >= 1) ? 16 * W1_LDS_STRIDE : 4];
    __shared__ float sAB1[64];
    __shared__ float sAB2[16];
    __shared__ float sred[4][2][32];

    const int tid = threadIdx.x;
    const int bid = blockIdx.x;

    // Stage W0 into LDS (padded per-type stride), vectorized
    {
        const float4* W04 = (const float4*)W0g;
        #pragma unroll
        for (int i = 0; i < 8; i++) {
            int g4 = tid + i * TPB;              // 0..2047 float4s
            float4 v = W04[g4];
            int t = g4 >> 7;                     // 128 float4 per type
            int rem = (g4 & 127) << 2;           // float offset in type
            *(float4*)(&sW0[t * W0_LDS_STRIDE + rem]) = v;
        }
    }
    if constexpr (PHASE >= 1) {
        // Stage W1 transposed: [t][h][n] so per-h reads are 8 contiguous floats
        #pragma unroll
        for (int i = 0; i < 16; i++) {
            int g = tid + i * TPB;               // 0..4095
            int t = g >> 8;
            int n = (g >> 5) & 7;
            int h = g & 31;
            sW1[t * W1_LDS_STRIDE + h * 8 + n] = W1g[g];
        }
        if (tid < 64) sAB1[tid] = ab1[tid];
    }
    if constexpr (PHASE == 2) {
        if (tid < 16) sAB2[tid] = ab2[tid];
    }
    __syncthreads();

    constexpr int NS = (PHASE == 0) ? 32 : (PHASE == 1 ? 8 : 1);
    float s1[NS], s2[NS];
    #pragma unroll
    for (int c = 0; c < NS; c++) { s1[c] = 0.f; s2[c] = 0.f; }

    #pragma unroll
    for (int k = 0; k < EPT; k++) {
        const int e = bid * (TPB * EPT) + k * TPB + tid;
        const int t = ij[e];
        const float4* f4 = (const float4*)(fn + (size_t)e * 16);
        float4 fa = f4[0], fb = f4[1], fc = f4[2], fd = f4[3];
        const float* w0t = &sW0[t * W0_LDS_STRIDE];
        const float* w1t = nullptr;
        if constexpr (PHASE >= 1) w1t = &sW1[t * W1_LDS_STRIDE];

        float o2[8];
        if constexpr (PHASE >= 1) {
            #pragma unroll
            for (int n = 0; n < 8; n++) o2[n] = 0.f;
        }

        #pragma unroll
        for (int h = 0; h < 32; h++) {
            const float4* wr = (const float4*)(w0t + h * 16);
            float4 wA = wr[0], wB = wr[1], wC = wr[2], wD = wr[3];
            float d = wA.x * fa.x + wA.y * fa.y + wA.z * fa.z + wA.w * fa.w
                    + wB.x * fb.x + wB.y * fb.y + wB.z * fb.z + wB.w * fb.w
                    + wC.x * fc.x + wC.y * fc.y + wC.z * fc.z + wC.w * fc.w
                    + wD.x * fd.x + wD.y * fd.y + wD.z * fd.z + wD.w * fd.w;
            if constexpr (PHASE == 0) {
                s1[h] += d;
                s2[h] += d * d;
            } else {
                float x = sAB1[h] * d + sAB1[32 + h];
                float a = silu_f(x);
                const float4* wn = (const float4*)(w1t + h * 8);
                float4 p = wn[0], q = wn[1];
                o2[0] += p.x * a; o2[1] += p.y * a; o2[2] += p.z * a; o2[3] += p.w * a;
                o2[4] += q.x * a; o2[5] += q.y * a; o2[6] += q.z * a; o2[7] += q.w * a;
            }
        }
        if constexpr (PHASE == 1) {
            #pragma unroll
            for (int n = 0; n < 8; n++) { s1[n] += o2[n]; s2[n] += o2[n] * o2[n]; }
        }
        if constexpr (PHASE == 2) {
            float r[8];
            #pragma unroll
            for (int n = 0; n < 8; n++) {
                float x = sAB2[n] * o2[n] + sAB2[8 + n];
                r[n] = silu_f(x);
            }
            float4 v0 = make_float4(r[0], r[1], r[2], r[3]);
            float4 v1 = make_float4(r[4], r[5], r[6], r[7]);
            *(float4*)(out + (size_t)e * 8)     = v0;
            *(float4*)(out + (size_t)e * 8 + 4) = v1;
        }
    }

    if constexpr (PHASE <= 1) {
        // Deterministic hierarchical reduction: wave shuffle -> LDS -> per-block partial
        const int lane = tid & 63;
        const int wid  = tid >> 6;
        #pragma unroll
        for (int c = 0; c < NS; c++) {
            float v1 = s1[c], v2 = s2[c];
            #pragma unroll
            for (int off = 32; off > 0; off >>= 1) {
                v1 += __shfl_down(v1, off, 64);
                v2 += __shfl_down(v2, off, 64);
            }
            if (lane == 0) { sred[wid][0][c] = v1; sred[wid][1][c] = v2; }
        }
        __syncthreads();
        if (tid < NS) {
            float a = sred[0][0][tid] + sred[1][0][tid] + sred[2][0][tid] + sred[3][0][tid];
            float b = sred[0][1][tid] + sred[1][1][tid] + sred[2][1][tid] + sred[3][1][tid];
            partial[bid * (2 * NS) + tid]      = a;
            partial[bid * (2 * NS) + NS + tid] = b;
        }
    }
}

// Reduce block partials; fold mean/var + gamma/beta into per-channel affine (a,b).
// Launch with NS*8 threads; 8-way parallel over blocks, LDS tree reduce.
template<int NS>
__global__ void nep_finalize(const float* __restrict__ partial,
                             const float* __restrict__ gamma,
                             const float* __restrict__ beta,
                             const int* __restrict__ norm,
                             float* __restrict__ ab)
{
    __shared__ float ssum[8][NS];
    __shared__ float ssq[8][NS];
    const int c = threadIdx.x & (NS - 1);
    const int j = threadIdx.x >> ((NS == 32) ? 5 : 3);
    float s = 0.f, q = 0.f;
    for (int blk = j; blk < NBLK; blk += 8) {
        s += partial[blk * (2 * NS) + c];
        q += partial[blk * (2 * NS) + NS + c];
    }
    ssum[j][c] = s; ssq[j][c] = q;
    __syncthreads();
    if (threadIdx.x < NS) {
        float st = 0.f, qt = 0.f;
        #pragma unroll
        for (int jj = 0; jj < 8; jj++) { st += ssum[jj][c]; qt += ssq[jj][c]; }
        const float invE = 1.0f / (float)E_TOTAL;
        float mean = st * invE;
        float var  = qt * invE - mean * mean;
        float inv  = rsqrtf(var + 1e-5f);
        float a, b;
        if (*norm) {
            a = gamma[c] * inv;
            b = beta[c] - mean * a;
        } else {
            a = 1.f; b = 0.f;
        }
        ab[c] = a;
        ab[NS + c] = b;
    }
}

extern "C" void kernel_launch(void* const* d_in, const int* in_sizes, int n_in,
                              void* d_out, int out_size, void* d_ws, size_t ws_size,
                              hipStream_t stream)
{
    const int*   ij   = (const int*)d_in[0];
    const float* fn   = (const float*)d_in[1];
    const float* W0   = (const float*)d_in[2];
    const float* W1   = (const float*)d_in[3];
    const float* g1   = (const float*)d_in[4];
    const float* b1   = (const float*)d_in[5];
    const float* g2   = (const float*)d_in[6];
    const float* b2   = (const float*)d_in[7];
    const int*   norm = (const int*)d_in[8];
    float* out = (float*)d_out;

    float* p1  = (float*)d_ws;            // NBLK * 64 floats
    float* p2  = p1 + NBLK * 64;          // NBLK * 16 floats
    float* ab1 = p2 + NBLK * 16;          // 64 floats
    float* ab2 = ab1 + 64;                // 16 floats

    nep_main<0><<<NBLK, TPB, 0, stream>>>(ij, fn, W0, W1, nullptr, nullptr, p1, nullptr);
    nep_finalize<32><<<1, 256, 0, stream>>>(p1, g1, b1, norm, ab1);
    nep_main<1><<<NBLK, TPB, 0, stream>>>(ij, fn, W0, W1, ab1, nullptr, p2, nullptr);
    nep_finalize<8><<<1, 64, 0, stream>>>(p2, g2, b2, norm, ab2);
    nep_main<2><<<NBLK, TPB, 0, stream>>>(ij, fn, W0, W1, ab1, ab2, nullptr, out);
}

// Round 3
// 98.879 us; speedup vs baseline: 3.5309x; 3.5309x over previous
//
#include <hip/hip_runtime.h>

#define E_TOTAL 262144
#define TPB 256
#define NBLK 1024
#define EPT 4
#define GPB (TPB/4)          // pair-groups (pairs) per block per k-iter = 64
#define W0S 516              // per-type float stride for sW0 (512 + 4 pad)
#define W1S 260              // per-type float stride for sW1 (256 + 4 pad)

__device__ __forceinline__ float silu_f(float x) {
    return x / (1.0f + __expf(-x));
}

// 4 lanes cooperate on one pair; lane (tid&3) owns channels h = lane*8 .. lane*8+7.
// PHASE 0: accumulate per-channel sum/sumsq of out1 (BN1 stats)
// PHASE 1: recompute out1, BN1+SiLU, second matvec -> o2[8] (shfl-combined), BN2 stats
// PHASE 2: full recompute, BN2+SiLU, write output
template<int PHASE>
__global__ __launch_bounds__(TPB, 4)
void nep_main(const int* __restrict__ ij,
              const float* __restrict__ fn,
              const float* __restrict__ W0g,
              const float* __restrict__ W1g,
              const float* __restrict__ ab1,
              const float* __restrict__ ab2,
              float* __restrict__ partial,
              float* __restrict__ out)
{
    __shared__ __align__(16) float sW0[16 * W0S];
    __shared__ __align__(16) float sW1[(PHASE >= 1) ? 16 * W1S : 4];
    __shared__ float sAB1[64];
    __shared__ float sAB2[16];
    __shared__ float sredS[4][32];
    __shared__ float sredQ[4][32];

    const int tid = threadIdx.x;
    const int bid = blockIdx.x;
    const int lane4 = tid & 3;
    const int grp = tid >> 2;

    // Stage W0 -> LDS with XOR block swizzle: row h block j stored at j ^ ((h>>3)&3).
    // Reader lanes (same t, h differing by 8) then hit 4 distinct 4-bank spans.
    {
        const float4* W04 = (const float4*)W0g;
        #pragma unroll
        for (int i = 0; i < 8; i++) {
            int g4 = tid + i * TPB;              // 0..2047
            float4 v = W04[g4];
            int t = g4 >> 7;
            int h = (g4 >> 2) & 31;
            int j = g4 & 3;
            int js = j ^ ((h >> 3) & 3);
            *(float4*)&sW0[t * W0S + h * 16 + js * 4] = v;
        }
    }
    if constexpr (PHASE >= 1) {
        // W1 global layout [t][n][h] -> LDS [t][h*8 + n]
        const float4* W14 = (const float4*)W1g;
        #pragma unroll
        for (int i = 0; i < 4; i++) {
            int g4 = tid + i * TPB;              // 0..1023
            float4 v = W14[g4];
            int g = g4 * 4;
            int t = g >> 8;
            int n = (g >> 5) & 7;
            int h0 = g & 31;                     // multiple of 4
            sW1[t * W1S + (h0 + 0) * 8 + n] = v.x;
            sW1[t * W1S + (h0 + 1) * 8 + n] = v.y;
            sW1[t * W1S + (h0 + 2) * 8 + n] = v.z;
            sW1[t * W1S + (h0 + 3) * 8 + n] = v.w;
        }
        if (tid < 64) sAB1[tid] = ab1[tid];
    }
    if constexpr (PHASE == 2) {
        if (tid < 16) sAB2[tid] = ab2[tid];
    }
    __syncthreads();

    float s1[8], s2[8];
    #pragma unroll
    for (int c = 0; c < 8; c++) { s1[c] = 0.f; s2[c] = 0.f; }

    #pragma unroll 1
    for (int k = 0; k < EPT; k++) {
        const int p = bid * (GPB * EPT) + k * GPB + grp;
        const int t = ij[p];
        const float4* f4 = (const float4*)(fn + (size_t)p * 16);
        float4 fa = f4[0], fb = f4[1], fc = f4[2], fd = f4[3];
        const float* w0t = &sW0[t * W0S];

        float o2[8];
        if constexpr (PHASE >= 1) {
            #pragma unroll
            for (int n = 0; n < 8; n++) o2[n] = 0.f;
        }

        #pragma unroll
        for (int hh = 0; hh < 8; hh++) {
            const int h = lane4 * 8 + hh;
            const float* wr = w0t + h * 16;
            const int x = lane4;                 // == (h>>3)&3
            float4 wA = *(const float4*)(wr + ((0 ^ x) << 2));
            float4 wB = *(const float4*)(wr + ((1 ^ x) << 2));
            float4 wC = *(const float4*)(wr + ((2 ^ x) << 2));
            float4 wD = *(const float4*)(wr + ((3 ^ x) << 2));
            float d = wA.x * fa.x + wA.y * fa.y + wA.z * fa.z + wA.w * fa.w
                    + wB.x * fb.x + wB.y * fb.y + wB.z * fb.z + wB.w * fb.w
                    + wC.x * fc.x + wC.y * fc.y + wC.z * fc.z + wC.w * fc.w
                    + wD.x * fd.x + wD.y * fd.y + wD.z * fd.z + wD.w * fd.w;
            if constexpr (PHASE == 0) {
                s1[hh] += d;
                s2[hh] += d * d;
            } else {
                float xv = sAB1[h] * d + sAB1[32 + h];
                float a = silu_f(xv);
                const float* wn = &sW1[t * W1S + h * 8];
                float4 pA = *(const float4*)(wn);
                float4 pB = *(const float4*)(wn + 4);
                o2[0] += pA.x * a; o2[1] += pA.y * a; o2[2] += pA.z * a; o2[3] += pA.w * a;
                o2[4] += pB.x * a; o2[5] += pB.y * a; o2[6] += pB.z * a; o2[7] += pB.w * a;
            }
            if (hh == 1 || hh == 3 || hh == 5) __builtin_amdgcn_sched_barrier(0);
        }

        if constexpr (PHASE >= 1) {
            // combine the 4 lanes' partial second-matvec results
            #pragma unroll
            for (int n = 0; n < 8; n++) {
                o2[n] += __shfl_xor(o2[n], 1, 64);
                o2[n] += __shfl_xor(o2[n], 2, 64);
            }
        }
        if constexpr (PHASE == 1) {
            if (lane4 == 0) {
                #pragma unroll
                for (int n = 0; n < 8; n++) { s1[n] += o2[n]; s2[n] += o2[n] * o2[n]; }
            }
        }
        if constexpr (PHASE == 2) {
            float r0 = silu_f(sAB2[0] * o2[0] + sAB2[8 + 0]);
            float r1 = silu_f(sAB2[1] * o2[1] + sAB2[8 + 1]);
            float r2 = silu_f(sAB2[2] * o2[2] + sAB2[8 + 2]);
            float r3 = silu_f(sAB2[3] * o2[3] + sAB2[8 + 3]);
            float r4 = silu_f(sAB2[4] * o2[4] + sAB2[8 + 4]);
            float r5 = silu_f(sAB2[5] * o2[5] + sAB2[8 + 5]);
            float r6 = silu_f(sAB2[6] * o2[6] + sAB2[8 + 6]);
            float r7 = silu_f(sAB2[7] * o2[7] + sAB2[8 + 7]);
            // lane4 writes elements {lane4*2, lane4*2+1}; static selects (no runtime reg-array idx)
            float e0 = (lane4 == 0) ? r0 : (lane4 == 1) ? r2 : (lane4 == 2) ? r4 : r6;
            float e1 = (lane4 == 0) ? r1 : (lane4 == 1) ? r3 : (lane4 == 2) ? r5 : r7;
            *(float2*)(out + (size_t)p * 8 + lane4 * 2) = make_float2(e0, e1);
        }
    }

    if constexpr (PHASE == 0) {
        // lane l holds stats for channels (l&3)*8+c ; sum across the 16 groups (strides 4..32)
        #pragma unroll
        for (int c = 0; c < 8; c++) {
            float v1 = s1[c], v2 = s2[c];
            v1 += __shfl_xor(v1, 4, 64);  v2 += __shfl_xor(v2, 4, 64);
            v1 += __shfl_xor(v1, 8, 64);  v2 += __shfl_xor(v2, 8, 64);
            v1 += __shfl_xor(v1, 16, 64); v2 += __shfl_xor(v2, 16, 64);
            v1 += __shfl_xor(v1, 32, 64); v2 += __shfl_xor(v2, 32, 64);
            s1[c] = v1; s2[c] = v2;
        }
        const int wid = tid >> 6;
        if ((tid & 63) < 4) {
            #pragma unroll
            for (int c = 0; c < 8; c++) {
                sredS[wid][lane4 * 8 + c] = s1[c];
                sredQ[wid][lane4 * 8 + c] = s2[c];
            }
        }
        __syncthreads();
        if (tid < 32) {
            float a = sredS[0][tid] + sredS[1][tid] + sredS[2][tid] + sredS[3][tid];
            float b = sredQ[0][tid] + sredQ[1][tid] + sredQ[2][tid] + sredQ[3][tid];
            partial[bid * 64 + tid]      = a;
            partial[bid * 64 + 32 + tid] = b;
        }
    }
    if constexpr (PHASE == 1) {
        // only lane4==0 lanes hold nonzero stats; strided butterfly sums the 16 leaders into lane 0
        #pragma unroll
        for (int c = 0; c < 8; c++) {
            float v1 = s1[c], v2 = s2[c];
            v1 += __shfl_xor(v1, 4, 64);  v2 += __shfl_xor(v2, 4, 64);
            v1 += __shfl_xor(v1, 8, 64);  v2 += __shfl_xor(v2, 8, 64);
            v1 += __shfl_xor(v1, 16, 64); v2 += __shfl_xor(v2, 16, 64);
            v1 += __shfl_xor(v1, 32, 64); v2 += __shfl_xor(v2, 32, 64);
            s1[c] = v1; s2[c] = v2;
        }
        const int wid = tid >> 6;
        if ((tid & 63) == 0) {
            #pragma unroll
            for (int n = 0; n < 8; n++) { sredS[wid][n] = s1[n]; sredQ[wid][n] = s2[n]; }
        }
        __syncthreads();
        if (tid < 8) {
            float a = sredS[0][tid] + sredS[1][tid] + sredS[2][tid] + sredS[3][tid];
            float b = sredQ[0][tid] + sredQ[1][tid] + sredQ[2][tid] + sredQ[3][tid];
            partial[bid * 16 + tid]     = a;
            partial[bid * 16 + 8 + tid] = b;
        }
    }
}

// Reduce block partials; fold mean/var + gamma/beta into per-channel affine (a,b).
// blockDim = NS*JW.
template<int NS, int JW>
__global__ void nep_finalize(const float* __restrict__ partial,
                             const float* __restrict__ gamma,
                             const float* __restrict__ beta,
                             const int* __restrict__ norm,
                             float* __restrict__ ab)
{
    __shared__ float ssum[JW][NS];
    __shared__ float ssq[JW][NS];
    const int c = threadIdx.x & (NS - 1);
    const int j = threadIdx.x / NS;
    float s = 0.f, q = 0.f;
    for (int blk = j; blk < NBLK; blk += JW) {
        s += partial[blk * (2 * NS) + c];
        q += partial[blk * (2 * NS) + NS + c];
    }
    ssum[j][c] = s; ssq[j][c] = q;
    __syncthreads();
    if (threadIdx.x < NS) {
        float st = 0.f, qt = 0.f;
        #pragma unroll
        for (int jj = 0; jj < JW; jj++) { st += ssum[jj][c]; qt += ssq[jj][c]; }
        const float invE = 1.0f / (float)E_TOTAL;
        float mean = st * invE;
        float var  = qt * invE - mean * mean;
        float inv  = rsqrtf(var + 1e-5f);
        float a, b;
        if (*norm) {
            a = gamma[c] * inv;
            b = beta[c] - mean * a;
        } else {
            a = 1.f; b = 0.f;
        }
        ab[c] = a;
        ab[NS + c] = b;
    }
}

extern "C" void kernel_launch(void* const* d_in, const int* in_sizes, int n_in,
                              void* d_out, int out_size, void* d_ws, size_t ws_size,
                              hipStream_t stream)
{
    const int*   ij   = (const int*)d_in[0];
    const float* fn   = (const float*)d_in[1];
    const float* W0   = (const float*)d_in[2];
    const float* W1   = (const float*)d_in[3];
    const float* g1   = (const float*)d_in[4];
    const float* b1   = (const float*)d_in[5];
    const float* g2   = (const float*)d_in[6];
    const float* b2   = (const float*)d_in[7];
    const int*   norm = (const int*)d_in[8];
    float* out = (float*)d_out;

    float* p1  = (float*)d_ws;            // NBLK * 64 floats
    float* p2  = p1 + NBLK * 64;          // NBLK * 16 floats
    float* ab1 = p2 + NBLK * 16;          // 64 floats
    float* ab2 = ab1 + 64;                // 16 floats

    nep_main<0><<<NBLK, TPB, 0, stream>>>(ij, fn, W0, W1, nullptr, nullptr, p1, nullptr);
    nep_finalize<32, 16><<<1, 512, 0, stream>>>(p1, g1, b1, norm, ab1);
    nep_main<1><<<NBLK, TPB, 0, stream>>>(ij, fn, W0, W1, ab1, nullptr, p2, nullptr);
    nep_finalize<8, 32><<<1, 256, 0, stream>>>(p2, g2, b2, norm, ab2);
    nep_main<2><<<NBLK, TPB, 0, stream>>>(ij, fn, W0, W1, ab1, ab2, nullptr, out);
}